// Round 1
// baseline (454.914 us; speedup 1.0000x reference)
//
#include <hip/hip_runtime.h>

// GMM (MoNet) graph conv, 2 layers. Gather formulation via CSR row_ptr -> no atomics.
// Pipeline: gauss[E,3] -> xW1[N,96] -> conv1 (h[N,32]) -> hW2[N,48] -> conv2 (out[N,16]).

#define KK 3

__global__ void gauss_kernel(const float* __restrict__ p, const float* __restrict__ mu,
                             const float* __restrict__ sigma, float* __restrict__ gauss, int E) {
    int e = blockIdx.x * blockDim.x + threadIdx.x;
    if (e >= E) return;
    float p0 = p[2 * e], p1 = p[2 * e + 1];
#pragma unroll
    for (int k = 0; k < KK; ++k) {
        float m0 = mu[2 * k], m1 = mu[2 * k + 1];
        float s0 = sigma[2 * k], s1 = sigma[2 * k + 1];
        float d0 = p0 - m0, d1 = p1 - m1;
        float q = (d0 * d0) / (s0 * s0) + (d1 * d1) / (s1 * s1);
        gauss[KK * e + k] = __expf(-0.5f * q);
    }
}

// y[n, k*H+h] = sum_f x[n,f] * W[k,f,h].  W staged in LDS transposed to [F][K*H]
// so the inner-loop LDS read is contiguous across the thread's j index.
template <int F, int H>
__global__ void xw_kernel(const float* __restrict__ x, const float* __restrict__ W,
                          float* __restrict__ y, int N) {
    constexpr int KH = KK * H;
    __shared__ float Ws[F * KH];
    for (int i = threadIdx.x; i < F * KH; i += blockDim.x) {
        int f = i / KH, j = i % KH;
        int k = j / H, hh = j % H;
        Ws[i] = W[(k * F + f) * H + hh];
    }
    __syncthreads();
    long long tid = (long long)blockIdx.x * blockDim.x + threadIdx.x;
    int n = (int)(tid / KH);
    int j = (int)(tid % KH);
    if (n >= N) return;
    const float* xr = x + (long long)n * F;
    float acc = 0.f;
#pragma unroll
    for (int f = 0; f < F; ++f) acc = fmaf(xr[f], Ws[f * KH + j], acc);
    y[(long long)n * KH + j] = acc;
}

// y[n,h] = sum_{e in row_ptr[n]..row_ptr[n+1]} sum_k gauss[e,k] * xw[col[e], k*H+h]
template <int H>
__global__ void conv_kernel(const int* __restrict__ row_ptr, const int* __restrict__ col_idx,
                            const float* __restrict__ gauss, const float* __restrict__ xw,
                            float* __restrict__ y, int N) {
    constexpr int KH = KK * H;
    long long tid = (long long)blockIdx.x * blockDim.x + threadIdx.x;
    int n = (int)(tid / H);
    int h = (int)(tid % H);
    if (n >= N) return;
    int e0 = row_ptr[n], e1 = row_ptr[n + 1];
    float acc = 0.f;
    for (int e = e0; e < e1; ++e) {
        int c = col_idx[e];
        float g0 = gauss[KK * e + 0];
        float g1 = gauss[KK * e + 1];
        float g2 = gauss[KK * e + 2];
        const float* xr = xw + (long long)c * KH + h;
        acc = fmaf(g0, xr[0], acc);
        acc = fmaf(g1, xr[H], acc);
        acc = fmaf(g2, xr[2 * H], acc);
    }
    y[(long long)n * H + h] = acc;
}

extern "C" void kernel_launch(void* const* d_in, const int* in_sizes, int n_in,
                              void* d_out, int out_size, void* d_ws, size_t ws_size,
                              hipStream_t stream) {
    const int* row_ptr  = (const int*)d_in[0];
    const int* col_idx  = (const int*)d_in[1];
    const float* x      = (const float*)d_in[2];
    const float* p      = (const float*)d_in[3];
    const float* mu     = (const float*)d_in[4];
    const float* sigma  = (const float*)d_in[5];
    const float* W1     = (const float*)d_in[6];
    const float* W2     = (const float*)d_in[7];

    const int N = in_sizes[0] - 1;   // row_ptr has N+1 entries
    const int E = in_sizes[1];

    float* gauss = (float*)d_ws;                 // E*3
    float* xw1   = gauss + (size_t)E * 3;        // N*96
    float* h     = xw1 + (size_t)N * 96;         // N*32
    float* hw2   = h + (size_t)N * 32;           // N*48
    float* out   = (float*)d_out;                // N*16

    const int B = 256;

    gauss_kernel<<<(E + B - 1) / B, B, 0, stream>>>(p, mu, sigma, gauss, E);

    {
        long long T = (long long)N * 96;
        xw_kernel<64, 32><<<(int)((T + B - 1) / B), B, 0, stream>>>(x, W1, xw1, N);
    }
    {
        long long T = (long long)N * 32;
        conv_kernel<32><<<(int)((T + B - 1) / B), B, 0, stream>>>(row_ptr, col_idx, gauss, xw1, h, N);
    }
    {
        long long T = (long long)N * 48;
        xw_kernel<32, 16><<<(int)((T + B - 1) / B), B, 0, stream>>>(h, W2, hw2, N);
    }
    {
        long long T = (long long)N * 16;
        conv_kernel<16><<<(int)((T + B - 1) / B), B, 0, stream>>>(row_ptr, col_idx, gauss, hw2, out, N);
    }
}

// Round 2
// 307.889 us; speedup vs baseline: 1.4775x; 1.4775x over previous
//
#include <hip/hip_runtime.h>

// GMM (MoNet) graph conv, 2 layers. Gather formulation via CSR row_ptr -> no atomics.
// Pipeline: gauss[E,3] -> xW1[N,96] -> conv1 (h[N,32]) -> hW2[N,48] -> conv2 (out[N,16]).
//
// R1 -> R2: replaced per-output-scalar xw_kernel (200us, 3 instrs/FMA) with a
// 64-node x 1-kernel tiled GEMM (W_k slice in LDS read via wave-uniform broadcast,
// x tile transposed in LDS stride-65 => conflict-free), and float4-vectorized the
// conv gather (3x dwordx4 + 12 FMA per edge instead of 12 scalar loads).

#define KK 3

__global__ void gauss_kernel(const float* __restrict__ p, const float* __restrict__ mu,
                             const float* __restrict__ sigma, float* __restrict__ gauss, int E) {
    int e = blockIdx.x * blockDim.x + threadIdx.x;
    if (e >= E) return;
    float p0 = p[2 * e], p1 = p[2 * e + 1];
#pragma unroll
    for (int k = 0; k < KK; ++k) {
        float m0 = mu[2 * k], m1 = mu[2 * k + 1];
        float s0 = sigma[2 * k], s1 = sigma[2 * k + 1];
        float d0 = p0 - m0, d1 = p1 - m1;
        float q = (d0 * d0) / (s0 * s0) + (d1 * d1) / (s1 * s1);
        gauss[KK * e + k] = __expf(-0.5f * q);
    }
}

// y[n, k*H + j] = sum_f x[n,f] * W[k,f,j]
// Block: 64 nodes (lane = node) x one k (blockIdx.y). 4 waves split H cols.
// Per f: 1 conflict-free ds_read_b32 (x) + wave-uniform broadcast float4 W reads + H/4*... FMAs.
template <int F, int H>
__global__ void xw_tiled(const float* __restrict__ x, const float* __restrict__ W,
                         float* __restrict__ y, int N) {
    constexpr int F4 = F / 4;
    constexpr int H4 = H / 4;
    constexpr int CJ = H / 4;      // cols per wave (4 waves): H=32 -> 8, H=16 -> 4
    constexpr int KH4 = KK * H4;   // float4s per output row

    __shared__ __align__(16) float xs[F * 65];
    __shared__ __align__(16) float ws[F * H];

    const int k  = blockIdx.y;
    const int n0 = blockIdx.x * 64;
    const int tid = threadIdx.x;

    // stage W[k] (contiguous F*H floats)
    const float4* Wk = (const float4*)(W + (size_t)k * F * H);
    for (int i = tid; i < F * H4; i += 256) ((float4*)ws)[i] = Wk[i];

    // stage x tile transposed: xs[f*65 + n]
    for (int i = tid; i < 64 * F4; i += 256) {
        int n = i / F4, fq = i % F4;
        float4 v = {0.f, 0.f, 0.f, 0.f};
        if (n0 + n < N) v = ((const float4*)x)[(size_t)(n0 + n) * F4 + fq];
        xs[(4 * fq + 0) * 65 + n] = v.x;
        xs[(4 * fq + 1) * 65 + n] = v.y;
        xs[(4 * fq + 2) * 65 + n] = v.z;
        xs[(4 * fq + 3) * 65 + n] = v.w;
    }
    __syncthreads();

    const int lane = tid & 63;     // node within tile
    const int wv   = tid >> 6;     // wave id -> col group
    const int cb   = wv * (CJ / 4);  // float4 col base within the k's H cols

    float4 acc0 = {0.f, 0.f, 0.f, 0.f};
    float4 acc1 = {0.f, 0.f, 0.f, 0.f};
    const float4* wsv = (const float4*)ws;

#pragma unroll 8
    for (int f = 0; f < F; ++f) {
        float xv = xs[f * 65 + lane];
        float4 wa = wsv[f * H4 + cb];
        acc0.x = fmaf(xv, wa.x, acc0.x);
        acc0.y = fmaf(xv, wa.y, acc0.y);
        acc0.z = fmaf(xv, wa.z, acc0.z);
        acc0.w = fmaf(xv, wa.w, acc0.w);
        if constexpr (CJ == 8) {
            float4 wb = wsv[f * H4 + cb + 1];
            acc1.x = fmaf(xv, wb.x, acc1.x);
            acc1.y = fmaf(xv, wb.y, acc1.y);
            acc1.z = fmaf(xv, wb.z, acc1.z);
            acc1.w = fmaf(xv, wb.w, acc1.w);
        }
    }

    if (n0 + lane < N) {
        float4* yv = (float4*)y;
        size_t rb = (size_t)(n0 + lane) * KH4 + (size_t)k * H4 + cb;
        yv[rb] = acc0;
        if constexpr (CJ == 8) yv[rb + 1] = acc1;
    }
}

// y[n, h4] = sum_{e in row} sum_k gauss[e,k] * xw[col[e], k*H + h4], float4 over cols.
template <int H>
__global__ void conv_v4(const int* __restrict__ row_ptr, const int* __restrict__ col_idx,
                        const float* __restrict__ gauss, const float* __restrict__ xw,
                        float* __restrict__ y, int N) {
    constexpr int HV = H / 4;       // float4 groups per k-plane
    constexpr int KH4 = KK * HV;    // float4s per xw row
    long long tid = (long long)blockIdx.x * blockDim.x + threadIdx.x;
    int n  = (int)(tid / HV);
    int hv = (int)(tid % HV);
    if (n >= N) return;

    const float4* xwv = (const float4*)xw;
    float4 acc = {0.f, 0.f, 0.f, 0.f};
    int e0 = row_ptr[n], e1 = row_ptr[n + 1];
    for (int e = e0; e < e1; ++e) {
        int c = col_idx[e];
        float g0 = gauss[KK * e + 0];
        float g1 = gauss[KK * e + 1];
        float g2 = gauss[KK * e + 2];
        size_t base = (size_t)c * KH4 + hv;
        float4 a = xwv[base];
        float4 b = xwv[base + HV];
        float4 d = xwv[base + 2 * HV];
        acc.x = fmaf(g0, a.x, acc.x); acc.y = fmaf(g0, a.y, acc.y);
        acc.z = fmaf(g0, a.z, acc.z); acc.w = fmaf(g0, a.w, acc.w);
        acc.x = fmaf(g1, b.x, acc.x); acc.y = fmaf(g1, b.y, acc.y);
        acc.z = fmaf(g1, b.z, acc.z); acc.w = fmaf(g1, b.w, acc.w);
        acc.x = fmaf(g2, d.x, acc.x); acc.y = fmaf(g2, d.y, acc.y);
        acc.z = fmaf(g2, d.z, acc.z); acc.w = fmaf(g2, d.w, acc.w);
    }
    ((float4*)y)[(size_t)n * HV + hv] = acc;
}

extern "C" void kernel_launch(void* const* d_in, const int* in_sizes, int n_in,
                              void* d_out, int out_size, void* d_ws, size_t ws_size,
                              hipStream_t stream) {
    const int* row_ptr  = (const int*)d_in[0];
    const int* col_idx  = (const int*)d_in[1];
    const float* x      = (const float*)d_in[2];
    const float* p      = (const float*)d_in[3];
    const float* mu     = (const float*)d_in[4];
    const float* sigma  = (const float*)d_in[5];
    const float* W1     = (const float*)d_in[6];
    const float* W2     = (const float*)d_in[7];

    const int N = in_sizes[0] - 1;   // row_ptr has N+1 entries
    const int E = in_sizes[1];

    float* gauss = (float*)d_ws;                 // E*3
    float* xw1   = gauss + (size_t)E * 3;        // N*96
    float* h     = xw1 + (size_t)N * 96;         // N*32
    float* hw2   = h + (size_t)N * 32;           // N*48
    float* out   = (float*)d_out;                // N*16

    const int B = 256;
    const int ntiles = (N + 63) / 64;

    gauss_kernel<<<(E + B - 1) / B, B, 0, stream>>>(p, mu, sigma, gauss, E);

    xw_tiled<64, 32><<<dim3(ntiles, KK), B, 0, stream>>>(x, W1, xw1, N);

    {
        long long T = (long long)N * 8;   // N * (32/4)
        conv_v4<32><<<(int)((T + B - 1) / B), B, 0, stream>>>(row_ptr, col_idx, gauss, xw1, h, N);
    }

    xw_tiled<32, 16><<<dim3(ntiles, KK), B, 0, stream>>>(h, W2, hw2, N);

    {
        long long T = (long long)N * 4;   // N * (16/4)
        conv_v4<16><<<(int)((T + B - 1) / B), B, 0, stream>>>(row_ptr, col_idx, gauss, hw2, out, N);
    }
}

// Round 3
// 231.650 us; speedup vs baseline: 1.9638x; 1.3291x over previous
//
#include <hip/hip_runtime.h>
#include <hip/hip_fp16.h>

// GMM (MoNet) graph conv, 2 layers. Gather formulation via CSR row_ptr -> no atomics.
// Pipeline: gauss4[E,4] -> xW1 (fp16 [N,96]) -> conv1 (h[N,32] fp32) -> hW2 (fp16 [N,48]) -> conv2 (out).
//
// R2 -> R3: gathered intermediates (xw1, hw2) stored fp16 (halves dominant random-gather
// traffic, fp32 accumulate); conv processes 4 edges per iteration with all loads hoisted
// (VGPR was 20 -> compiler had ~1 edge in flight); gauss padded to float4 for 1-load reads.

#define KK 3

__global__ void gauss_kernel(const float* __restrict__ p, const float* __restrict__ mu,
                             const float* __restrict__ sigma, float4* __restrict__ gauss4, int E) {
    int e = blockIdx.x * blockDim.x + threadIdx.x;
    if (e >= E) return;
    float p0 = p[2 * e], p1 = p[2 * e + 1];
    float4 g;
    float* gp = (float*)&g;
#pragma unroll
    for (int k = 0; k < KK; ++k) {
        float m0 = mu[2 * k], m1 = mu[2 * k + 1];
        float s0 = sigma[2 * k], s1 = sigma[2 * k + 1];
        float d0 = p0 - m0, d1 = p1 - m1;
        float q = (d0 * d0) / (s0 * s0) + (d1 * d1) / (s1 * s1);
        gp[k] = __expf(-0.5f * q);
    }
    g.w = 0.f;
    gauss4[e] = g;
}

// y[n, k*H + j] = sum_f x[n,f] * W[k,f,j], output fp16.
// Block: 64 nodes (lane = node) x one k (blockIdx.y). 4 waves split H cols.
template <int F, int H>
__global__ void xw_tiled(const float* __restrict__ x, const float* __restrict__ W,
                         __half* __restrict__ y, int N) {
    constexpr int F4 = F / 4;
    constexpr int H4 = H / 4;
    constexpr int CJ = H / 4;      // cols per wave (4 waves): H=32 -> 8, H=16 -> 4
    constexpr int KH = KK * H;     // halves per output row

    __shared__ __align__(16) float xs[F * 65];
    __shared__ __align__(16) float ws[F * H];

    const int k  = blockIdx.y;
    const int n0 = blockIdx.x * 64;
    const int tid = threadIdx.x;

    const float4* Wk = (const float4*)(W + (size_t)k * F * H);
    for (int i = tid; i < F * H4; i += 256) ((float4*)ws)[i] = Wk[i];

    for (int i = tid; i < 64 * F4; i += 256) {
        int n = i / F4, fq = i % F4;
        float4 v = {0.f, 0.f, 0.f, 0.f};
        if (n0 + n < N) v = ((const float4*)x)[(size_t)(n0 + n) * F4 + fq];
        xs[(4 * fq + 0) * 65 + n] = v.x;
        xs[(4 * fq + 1) * 65 + n] = v.y;
        xs[(4 * fq + 2) * 65 + n] = v.z;
        xs[(4 * fq + 3) * 65 + n] = v.w;
    }
    __syncthreads();

    const int lane = tid & 63;
    const int wv   = tid >> 6;
    const int cb   = wv * (CJ / 4);   // float4 col base

    float4 acc0 = {0.f, 0.f, 0.f, 0.f};
    float4 acc1 = {0.f, 0.f, 0.f, 0.f};
    const float4* wsv = (const float4*)ws;

#pragma unroll 8
    for (int f = 0; f < F; ++f) {
        float xv = xs[f * 65 + lane];
        float4 wa = wsv[f * H4 + cb];
        acc0.x = fmaf(xv, wa.x, acc0.x);
        acc0.y = fmaf(xv, wa.y, acc0.y);
        acc0.z = fmaf(xv, wa.z, acc0.z);
        acc0.w = fmaf(xv, wa.w, acc0.w);
        if constexpr (CJ == 8) {
            float4 wb = wsv[f * H4 + cb + 1];
            acc1.x = fmaf(xv, wb.x, acc1.x);
            acc1.y = fmaf(xv, wb.y, acc1.y);
            acc1.z = fmaf(xv, wb.z, acc1.z);
            acc1.w = fmaf(xv, wb.w, acc1.w);
        }
    }

    if (n0 + lane < N) {
        __half* row = y + (size_t)(n0 + lane) * KH + k * H + wv * CJ;
        if constexpr (CJ == 8) {
            union { __half h[8]; float4 f; } o;
            o.h[0] = __float2half(acc0.x); o.h[1] = __float2half(acc0.y);
            o.h[2] = __float2half(acc0.z); o.h[3] = __float2half(acc0.w);
            o.h[4] = __float2half(acc1.x); o.h[5] = __float2half(acc1.y);
            o.h[6] = __float2half(acc1.z); o.h[7] = __float2half(acc1.w);
            *(float4*)row = o.f;
        } else {
            union { __half h[4]; float2 f; } o;
            o.h[0] = __float2half(acc0.x); o.h[1] = __float2half(acc0.y);
            o.h[2] = __float2half(acc0.z); o.h[3] = __float2half(acc0.w);
            *(float2*)row = o.f;
        }
    }
}

__device__ __forceinline__ void fma_h4(float4& acc, float g, float2 raw) {
    union { float2 f; __half2 h[2]; } u;
    u.f = raw;
    float2 a = __half22float2(u.h[0]);
    float2 b = __half22float2(u.h[1]);
    acc.x = fmaf(g, a.x, acc.x);
    acc.y = fmaf(g, a.y, acc.y);
    acc.z = fmaf(g, b.x, acc.z);
    acc.w = fmaf(g, b.y, acc.w);
}

// y[n, 4hv..4hv+3] = sum_e sum_k gauss[e,k] * xw_h[col[e], k*H + 4hv..], fp16 gather, fp32 accum.
// 4 edges per iteration: all 4 col + 4 gauss + 12 xw loads hoisted ahead of the FMAs.
template <int H>
__global__ void conv_f16(const int* __restrict__ row_ptr, const int* __restrict__ col_idx,
                         const float4* __restrict__ gauss4, const __half* __restrict__ xw,
                         float* __restrict__ y, int N) {
    constexpr int HV = H / 4;
    constexpr int KH = KK * H;     // halves per row
    long long tid = (long long)blockIdx.x * blockDim.x + threadIdx.x;
    int n  = (int)(tid / HV);
    int hv = (int)(tid % HV);
    if (n >= N) return;

    int e0 = row_ptr[n], e1 = row_ptr[n + 1];
    float4 acc = {0.f, 0.f, 0.f, 0.f};
    int e = e0;
    for (; e + 4 <= e1; e += 4) {
        int c[4];
        float4 g[4];
        float2 r[4][3];
#pragma unroll
        for (int j = 0; j < 4; ++j) c[j] = col_idx[e + j];
#pragma unroll
        for (int j = 0; j < 4; ++j) g[j] = gauss4[e + j];
#pragma unroll
        for (int j = 0; j < 4; ++j) {
            const __half* row = xw + (size_t)c[j] * KH + hv * 4;
            r[j][0] = *(const float2*)(row);
            r[j][1] = *(const float2*)(row + H);
            r[j][2] = *(const float2*)(row + 2 * H);
        }
#pragma unroll
        for (int j = 0; j < 4; ++j) {
            fma_h4(acc, g[j].x, r[j][0]);
            fma_h4(acc, g[j].y, r[j][1]);
            fma_h4(acc, g[j].z, r[j][2]);
        }
    }
    for (; e < e1; ++e) {
        int c = col_idx[e];
        float4 g = gauss4[e];
        const __half* row = xw + (size_t)c * KH + hv * 4;
        fma_h4(acc, g.x, *(const float2*)(row));
        fma_h4(acc, g.y, *(const float2*)(row + H));
        fma_h4(acc, g.z, *(const float2*)(row + 2 * H));
    }
    ((float4*)y)[(size_t)n * HV + hv] = acc;
}

extern "C" void kernel_launch(void* const* d_in, const int* in_sizes, int n_in,
                              void* d_out, int out_size, void* d_ws, size_t ws_size,
                              hipStream_t stream) {
    const int* row_ptr  = (const int*)d_in[0];
    const int* col_idx  = (const int*)d_in[1];
    const float* x      = (const float*)d_in[2];
    const float* p      = (const float*)d_in[3];
    const float* mu     = (const float*)d_in[4];
    const float* sigma  = (const float*)d_in[5];
    const float* W1     = (const float*)d_in[6];
    const float* W2     = (const float*)d_in[7];

    const int N = in_sizes[0] - 1;
    const int E = in_sizes[1];

    float4* gauss4 = (float4*)d_ws;                       // E float4s
    float*  h      = (float*)(gauss4 + (size_t)E);        // N*32 f32
    __half* xw1h   = (__half*)(h + (size_t)N * 32);       // N*96 fp16
    __half* hw2h   = xw1h + (size_t)N * 96;               // N*48 fp16
    float*  out    = (float*)d_out;                       // N*16 f32

    const int B = 256;
    const int ntiles = (N + 63) / 64;

    gauss_kernel<<<(E + B - 1) / B, B, 0, stream>>>(p, mu, sigma, gauss4, E);

    xw_tiled<64, 32><<<dim3(ntiles, KK), B, 0, stream>>>(x, W1, xw1h, N);

    {
        long long T = (long long)N * 8;
        conv_f16<32><<<(int)((T + B - 1) / B), B, 0, stream>>>(row_ptr, col_idx, gauss4, xw1h, h, N);
    }

    xw_tiled<32, 16><<<dim3(ntiles, KK), B, 0, stream>>>(h, W2, hw2h, N);

    {
        long long T = (long long)N * 4;
        conv_f16<16><<<(int)((T + B - 1) / B), B, 0, stream>>>(row_ptr, col_idx, gauss4, hw2h, out, N);
    }
}